// Round 3
// baseline (742.268 us; speedup 1.0000x reference)
//
#include <hip/hip_runtime.h>
#include <hip/hip_fp16.h>
#include <cstdint>
#include <cstddef>

// Problem constants (match reference)
#define Bn   2
#define Wn   8
#define Nn   10000
#define Fin  5
#define En   80000
#define Hn   128
#define BWn  (Bn*Wn)        // 16
#define ROWS (BWn*Nn)       // 160000
#define MR   (Bn*Nn)        // 20000  (LSTM batch rows)

typedef _Float16 half8 __attribute__((ext_vector_type(8)));
typedef float f32x4 __attribute__((ext_vector_type(4)));

// ---------------- CSR build ----------------

__global__ void init_counts_kernel(int* counts) {
    int i = blockIdx.x * blockDim.x + threadIdx.x;
    if (i < Nn) counts[i] = 1;   // self-loop contributes 1 to every dst
}

__global__ void count_edges_kernel(const int* __restrict__ ei, int* counts) {
    int e = blockIdx.x * blockDim.x + threadIdx.x;
    if (e < En) atomicAdd(&counts[ei[En + e]], 1);   // dst row
}

enum { CHUNK = 10 };  // ceil(10000/1024)
static_assert(CHUNK * 1024 >= Nn, "scan chunk");

__global__ __launch_bounds__(1024) void scan_kernel(
    const int* __restrict__ counts, int* __restrict__ row_ptr,
    int* __restrict__ fill_ptr, float* __restrict__ dinv) {
    __shared__ int sums[1024];
    const int t = threadIdx.x;
    const int base = t * CHUNK;
    int cnt[CHUNK];
    int s = 0;
    #pragma unroll
    for (int i = 0; i < CHUNK; ++i) {
        int idx = base + i;
        int v = (idx < Nn) ? counts[idx] : 0;
        cnt[i] = v; s += v;
    }
    sums[t] = s;
    __syncthreads();
    for (int off = 1; off < 1024; off <<= 1) {
        int v = (t >= off) ? sums[t - off] : 0;
        __syncthreads();
        sums[t] += v;
        __syncthreads();
    }
    int excl = (t == 0) ? 0 : sums[t - 1];
    #pragma unroll
    for (int i = 0; i < CHUNK; ++i) {
        int idx = base + i;
        if (idx < Nn) {
            row_ptr[idx] = excl;
            fill_ptr[idx] = excl;
            dinv[idx] = rsqrtf((float)cnt[i]);
            excl += cnt[i];
        }
    }
    if (t == 1023) row_ptr[Nn] = excl;   // = E + N
}

__global__ void fill_kernel(const int* __restrict__ ei,
                            const float* __restrict__ dinv,
                            int* fill_ptr, int* __restrict__ col,
                            float* __restrict__ wgt) {
    int i = blockIdx.x * blockDim.x + threadIdx.x;
    if (i < Nn) {
        int p = atomicAdd(&fill_ptr[i], 1);
        col[p] = i;
        wgt[p] = dinv[i] * dinv[i];
    } else if (i < Nn + En) {
        int e = i - Nn;
        int s = ei[e];
        int d = ei[En + e];
        int p = atomicAdd(&fill_ptr[d], 1);
        col[p] = s;
        wgt[p] = dinv[s] * dinv[d];
    }
}

// ---------------- small helpers ----------------

__global__ void bsum_kernel(const float* __restrict__ a, const float* __restrict__ b,
                            float* __restrict__ out) {
    int i = blockIdx.x * blockDim.x + threadIdx.x;
    if (i < 4 * Hn) out[i] = a[i] + b[i];
}

// fp32 -> f16 weight conversion: wih (512x128), whh (512x128) direct; g2w (128x128) transposed
__global__ void convert_w_kernel(const float* __restrict__ wih, const float* __restrict__ whh,
                                 const float* __restrict__ g2w,
                                 _Float16* __restrict__ wihf, _Float16* __restrict__ whhf,
                                 _Float16* __restrict__ g2wt) {
    int i = blockIdx.x * blockDim.x + threadIdx.x;
    if (i < 65536) {
        wihf[i] = (_Float16)wih[i];
    } else if (i < 131072) {
        whhf[i - 65536] = (_Float16)whh[i - 65536];
    } else if (i < 131072 + 16384) {
        int j = i - 131072;           // output index into g2wt[n][k]
        int n = j >> 7, k = j & 127;
        g2wt[j] = (_Float16)g2w[k * Hn + n];
    }
}

// ---------------- GCN layer 1: aggregate x FIRST (F=5), then transform ----------------
__global__ __launch_bounds__(128) void agg_x_kernel(
    const float* __restrict__ x, const int* __restrict__ row_ptr,
    const int* __restrict__ col, const float* __restrict__ wgt,
    float* __restrict__ aggx) {
    const int n = blockIdx.x;
    const int t = threadIdx.x;
    const int s = t >> 3, f = t & 7;
    if (f >= Fin) return;
    const int start = row_ptr[n], end = row_ptr[n + 1];
    float acc = 0.f;
    for (int e = start; e < end; ++e) {
        int c = col[e];
        acc = fmaf(wgt[e], x[((size_t)s * Nn + c) * Fin + f], acc);
    }
    aggx[((size_t)s * Nn + n) * Fin + f] = acc;
}

// h1[row][j] = relu(aggx[row][:] @ W1[:,j] + b1[j]), output f16
__global__ void gemm1f_kernel(const float* __restrict__ aggx, const float* __restrict__ w,
                              const float* __restrict__ bias, _Float16* __restrict__ out) {
    int idx = blockIdx.x * blockDim.x + threadIdx.x;
    if (idx >= ROWS * Hn) return;
    int row = idx >> 7, j = idx & 127;
    const float* ar = aggx + (size_t)row * Fin;
    float s = bias[j];
    #pragma unroll
    for (int f = 0; f < Fin; ++f) s = fmaf(ar[f], w[f * Hn + j], s);
    out[idx] = (_Float16)fmaxf(s, 0.f);
}

// ---------------- GCN layer 2 aggregation, vectorized: 16 B/lane gather ----------------
// block = 256 threads = (slice s = t>>4) x (f-octet g = t&15); one dst node per block.
__global__ __launch_bounds__(256) void gcn_agg2_kernel(
    const _Float16* __restrict__ ht, const int* __restrict__ row_ptr,
    const int* __restrict__ col, const float* __restrict__ wgt,
    const float* __restrict__ bias, _Float16* __restrict__ out) {
    const int n = blockIdx.x;
    const int t = threadIdx.x;
    const int s = t >> 4;
    const int g = (t & 15) * 8;
    const int start = row_ptr[n], end = row_ptr[n + 1];
    float acc[8];
    #pragma unroll
    for (int j = 0; j < 8; ++j) acc[j] = 0.f;
    for (int e = start; e < end; ++e) {
        const int c = col[e];
        const float w = wgt[e];
        half8 v = *(const half8*)(ht + ((size_t)s * Nn + c) * Hn + g);
        #pragma unroll
        for (int j = 0; j < 8; ++j) acc[j] = fmaf(w, (float)v[j], acc[j]);
    }
    half8 o;
    #pragma unroll
    for (int j = 0; j < 8; ++j) o[j] = (_Float16)fmaxf(acc[j] + bias[g + j], 0.f);
    *(half8*)(out + ((size_t)s * Nn + n) * Hn + g) = o;
}

// ---------------- generic f16 MFMA GEMM: C = A @ B^T (+bias), K=128 ----------------
// B stored [n][k] row-major. BM=BN=128, BK=32; 4 waves, each 64x64 via 4x4 of 16x16x32.
__global__ __launch_bounds__(256) void gemm_f16_kernel(
    const _Float16* __restrict__ A, const _Float16* __restrict__ B,
    const float* __restrict__ bias, _Float16* __restrict__ C,
    int M, int Nc) {
    __shared__ _Float16 As[128][40];
    __shared__ _Float16 Bs[128][40];
    const int tid = threadIdx.x;
    const int m0 = blockIdx.x * 128;
    const int n0 = blockIdx.y * 128;
    const int wave = tid >> 6;
    const int lane = tid & 63;
    const int l = lane & 15, q = lane >> 4;
    const int wm = (wave & 1) * 64, wn = (wave >> 1) * 64;
    f32x4 acc[4][4];
    #pragma unroll
    for (int i = 0; i < 4; ++i)
        #pragma unroll
        for (int j = 0; j < 4; ++j)
            acc[i][j] = (f32x4){0.f, 0.f, 0.f, 0.f};

    for (int kt = 0; kt < 128; kt += 32) {
        #pragma unroll
        for (int j = 0; j < 2; ++j) {
            int idx = tid + j * 256;
            int r = idx >> 2, c = (idx & 3) * 8;
            int gr = m0 + r;
            half8 v = {0, 0, 0, 0, 0, 0, 0, 0};
            if (gr < M) v = *(const half8*)(A + (size_t)gr * 128 + kt + c);
            *(half8*)&As[r][c] = v;
            int nr = n0 + r;   // Nc multiple of 128 -> no guard
            *(half8*)&Bs[r][c] = *(const half8*)(B + (size_t)nr * 128 + kt + c);
        }
        __syncthreads();
        half8 af[4], bf[4];
        #pragma unroll
        for (int i = 0; i < 4; ++i) af[i] = *(const half8*)&As[wm + i * 16 + l][q * 8];
        #pragma unroll
        for (int j = 0; j < 4; ++j) bf[j] = *(const half8*)&Bs[wn + j * 16 + l][q * 8];
        #pragma unroll
        for (int i = 0; i < 4; ++i)
            #pragma unroll
            for (int j = 0; j < 4; ++j)
                acc[i][j] = __builtin_amdgcn_mfma_f32_16x16x32_f16(
                    af[i], bf[j], acc[i][j], 0, 0, 0);
        __syncthreads();
    }
    // epilogue: C/D layout col=lane&15, row=(lane>>4)*4+reg
    #pragma unroll
    for (int j = 0; j < 4; ++j) {
        int gcol = n0 + wn + j * 16 + l;
        float bv = bias ? bias[gcol] : 0.f;
        #pragma unroll
        for (int i = 0; i < 4; ++i) {
            #pragma unroll
            for (int r = 0; r < 4; ++r) {
                int grow = m0 + wm + i * 16 + q * 4 + r;
                if (grow < M)
                    C[(size_t)grow * Nc + gcol] = (_Float16)(acc[i][j][r] + bv);
            }
        }
    }
}

// ---------------- LSTM per-step GEMM: gates = hf @ whh^T + xg[step slice] ----------------
__global__ __launch_bounds__(256) void lstm_gemm_kernel(
    const _Float16* __restrict__ A,    // MR x 128 (h state)
    const _Float16* __restrict__ B,    // 512 x 128 (whh, n x k)
    const _Float16* __restrict__ xg,   // ROWS x 512 (x-part + bias, precomputed)
    _Float16* __restrict__ C,          // MR x 512 (gates)
    int step) {
    __shared__ _Float16 As[128][40];
    __shared__ _Float16 Bs[128][40];
    const int tid = threadIdx.x;
    const int m0 = blockIdx.x * 128;
    const int n0 = blockIdx.y * 128;
    const int wave = tid >> 6;
    const int lane = tid & 63;
    const int l = lane & 15, q = lane >> 4;
    const int wm = (wave & 1) * 64, wn = (wave >> 1) * 64;
    f32x4 acc[4][4];
    #pragma unroll
    for (int i = 0; i < 4; ++i)
        #pragma unroll
        for (int j = 0; j < 4; ++j)
            acc[i][j] = (f32x4){0.f, 0.f, 0.f, 0.f};

    for (int kt = 0; kt < 128; kt += 32) {
        #pragma unroll
        for (int j = 0; j < 2; ++j) {
            int idx = tid + j * 256;
            int r = idx >> 2, c = (idx & 3) * 8;
            int gr = m0 + r;
            half8 v = {0, 0, 0, 0, 0, 0, 0, 0};
            if (gr < MR) v = *(const half8*)(A + (size_t)gr * 128 + kt + c);
            *(half8*)&As[r][c] = v;
            int nr = n0 + r;   // Nc=512
            *(half8*)&Bs[r][c] = *(const half8*)(B + (size_t)nr * 128 + kt + c);
        }
        __syncthreads();
        half8 af[4], bf[4];
        #pragma unroll
        for (int i = 0; i < 4; ++i) af[i] = *(const half8*)&As[wm + i * 16 + l][q * 8];
        #pragma unroll
        for (int j = 0; j < 4; ++j) bf[j] = *(const half8*)&Bs[wn + j * 16 + l][q * 8];
        #pragma unroll
        for (int i = 0; i < 4; ++i)
            #pragma unroll
            for (int j = 0; j < 4; ++j)
                acc[i][j] = __builtin_amdgcn_mfma_f32_16x16x32_f16(
                    af[i], bf[j], acc[i][j], 0, 0, 0);
        __syncthreads();
    }
    #pragma unroll
    for (int j = 0; j < 4; ++j) {
        int gcol = n0 + wn + j * 16 + l;
        #pragma unroll
        for (int i = 0; i < 4; ++i) {
            #pragma unroll
            for (int r = 0; r < 4; ++r) {
                int grow = m0 + wm + i * 16 + q * 4 + r;
                if (grow < MR) {
                    int b = (grow >= Nn) ? 1 : 0;
                    size_t xrow = (size_t)(b * Wn + step) * Nn + (grow - b * Nn);
                    float xv = (float)xg[xrow * 512 + gcol];
                    C[(size_t)grow * 512 + gcol] = (_Float16)(acc[i][j][r] + xv);
                }
            }
        }
    }
}

// ---------------- LSTM pointwise ----------------
__global__ void lstm_pointwise_kernel(const _Float16* __restrict__ gates,
                                      _Float16* __restrict__ h, float* __restrict__ c) {
    int idx = blockIdx.x * blockDim.x + threadIdx.x;
    if (idx >= MR * Hn) return;
    int r = idx >> 7;
    int j = idx & 127;
    const _Float16* g = gates + (size_t)r * (4 * Hn);
    float gi = (float)g[j];
    float gf = (float)g[Hn + j];
    float gg = (float)g[2 * Hn + j];
    float go = (float)g[3 * Hn + j];
    float si = 1.f / (1.f + expf(-gi));
    float sf = 1.f / (1.f + expf(-gf));
    float so = 1.f / (1.f + expf(-go));
    float tg = tanhf(gg);
    float cn = sf * c[idx] + si * tg;
    c[idx] = cn;
    h[idx] = (_Float16)(so * tanhf(cn));
}

// ---------------- decoder ----------------
__global__ __launch_bounds__(256) void decoder_kernel(
    const _Float16* __restrict__ h, const float* __restrict__ w1,
    const float* __restrict__ b1, const float* __restrict__ w2,
    const float* __restrict__ b2, float* __restrict__ out) {
    const int wave = threadIdx.x >> 6;
    const int lane = threadIdx.x & 63;
    const int row = blockIdx.x * 4 + wave;
    if (row >= MR) return;
    const _Float16* hr = h + (size_t)row * Hn;
    float d = b1[lane];
    #pragma unroll 8
    for (int k = 0; k < Hn; ++k) d = fmaf((float)hr[k], w1[k * 64 + lane], d);
    d = fmaxf(d, 0.f);
    float p = d * w2[lane];
    #pragma unroll
    for (int off = 32; off; off >>= 1) p += __shfl_down(p, off);
    if (lane == 0) out[row] = p + b2[0];
}

// ---------------- launch ----------------

extern "C" void kernel_launch(void* const* d_in, const int* in_sizes, int n_in,
                              void* d_out, int out_size, void* d_ws, size_t ws_size,
                              hipStream_t stream) {
    const float* x   = (const float*)d_in[0];
    const int*   ei  = (const int*)d_in[1];
    const float* g1w = (const float*)d_in[2];
    const float* g1b = (const float*)d_in[3];
    const float* g2w = (const float*)d_in[4];
    const float* g2b = (const float*)d_in[5];
    const float* wih = (const float*)d_in[6];
    const float* whh = (const float*)d_in[7];
    const float* bih = (const float*)d_in[8];
    const float* bhh = (const float*)d_in[9];
    const float* dw1 = (const float*)d_in[10];
    const float* db1 = (const float*)d_in[11];
    const float* dw2 = (const float*)d_in[12];
    const float* db2 = (const float*)d_in[13];
    float* out = (float*)d_out;

    // workspace carve (256B aligned)
    char* p = (char*)d_ws;
    auto alloc = [&](size_t bytes) {
        char* r = p;
        p += (bytes + 255) & ~(size_t)255;
        return r;
    };
    int*      counts   = (int*)     alloc(Nn * 4);
    int*      row_ptr  = (int*)     alloc((Nn + 1) * 4);
    int*      fill_ptr = (int*)     alloc((Nn + 1) * 4);
    float*    dinv     = (float*)   alloc(Nn * 4);
    float*    bsum     = (float*)   alloc(4 * Hn * 4);
    int*      col      = (int*)     alloc((En + Nn) * 4);
    float*    wgt      = (float*)   alloc((En + Nn) * 4);
    _Float16* wihf     = (_Float16*)alloc(512 * 128 * 2);
    _Float16* whhf     = (_Float16*)alloc(512 * 128 * 2);
    _Float16* g2wt     = (_Float16*)alloc(128 * 128 * 2);
    float*    aggx     = (float*)   alloc((size_t)ROWS * Fin * 4);    // 3.2 MB
    _Float16* h2f      = (_Float16*)alloc((size_t)ROWS * Hn * 2);     // 41 MB
    _Float16* gates    = (_Float16*)alloc((size_t)MR * 4 * Hn * 2);   // 20.5 MB
    _Float16* hf       = (_Float16*)alloc((size_t)MR * Hn * 2);       // 5.1 MB
    float*    c_state  = (float*)   alloc((size_t)MR * Hn * 4);       // 10.2 MB
    // xg (164 MB) aliases h1f (first 41 MB) and htf (next 41 MB): both are dead
    // before xg is written (h1f -> htf -> h2f chain completes first).
    _Float16* xg       = (_Float16*)alloc((size_t)ROWS * 4 * Hn * 2); // 164 MB
    _Float16* h1f      = xg;
    _Float16* htf      = xg + (size_t)ROWS * Hn;

    // ---- CSR build + weight prep ----
    init_counts_kernel<<<(Nn + 255) / 256, 256, 0, stream>>>(counts);
    count_edges_kernel<<<(En + 255) / 256, 256, 0, stream>>>(ei, counts);
    scan_kernel<<<1, 1024, 0, stream>>>(counts, row_ptr, fill_ptr, dinv);
    fill_kernel<<<(Nn + En + 255) / 256, 256, 0, stream>>>(ei, dinv, fill_ptr, col, wgt);
    bsum_kernel<<<(4 * Hn + 255) / 256, 256, 0, stream>>>(bih, bhh, bsum);
    convert_w_kernel<<<(131072 + 16384 + 255) / 256, 256, 0, stream>>>(
        wih, whh, g2w, wihf, whhf, g2wt);

    // ---- GCN layer 1: aggregate (F=5) then transform ----
    agg_x_kernel<<<Nn, 128, 0, stream>>>(x, row_ptr, col, wgt, aggx);
    gemm1f_kernel<<<(ROWS * Hn + 255) / 256, 256, 0, stream>>>(aggx, g1w, g1b, h1f);

    // ---- GCN layer 2: transform (MFMA) then aggregate ----
    gemm_f16_kernel<<<dim3(ROWS / 128, 1), 256, 0, stream>>>(
        h1f, g2wt, nullptr, htf, ROWS, Hn);
    gcn_agg2_kernel<<<Nn, 256, 0, stream>>>(htf, row_ptr, col, wgt, g2b, h2f);

    // ---- LSTM: precompute x-part for all 16 (b,t) slices in one GEMM ----
    gemm_f16_kernel<<<dim3(ROWS / 128, 4), 256, 0, stream>>>(
        h2f, wihf, bsum, xg, ROWS, 4 * Hn);

    hipMemsetAsync(hf, 0, (size_t)MR * Hn * 2, stream);
    hipMemsetAsync(c_state, 0, (size_t)MR * Hn * 4, stream);
    const int mtiles = (MR + 127) / 128;   // 157
    for (int t = 0; t < Wn; ++t) {
        lstm_gemm_kernel<<<dim3(mtiles, 4), 256, 0, stream>>>(
            hf, whhf, xg, gates, t);
        lstm_pointwise_kernel<<<(MR * Hn + 255) / 256, 256, 0, stream>>>(
            gates, hf, c_state);
    }

    // ---- decoder ----
    decoder_kernel<<<(MR + 3) / 4, 256, 0, stream>>>(hf, dw1, db1, dw2, db2, out);
}

// Round 4
// 469.888 us; speedup vs baseline: 1.5797x; 1.5797x over previous
//
#include <hip/hip_runtime.h>
#include <hip/hip_fp16.h>
#include <cstdint>
#include <cstddef>

// Problem constants (match reference)
#define Bn   2
#define Wn   8
#define Nn   10000
#define Fin  5
#define En   80000
#define Hn   128
#define BWn  (Bn*Wn)        // 16
#define ROWS (BWn*Nn)       // 160000
#define MR   (Bn*Nn)        // 20000  (LSTM batch rows)
#define NT_SLICE 625        // 10000/16 row-tiles per slice

typedef _Float16 half8 __attribute__((ext_vector_type(8)));
typedef _Float16 half4 __attribute__((ext_vector_type(4)));
typedef float f32x4 __attribute__((ext_vector_type(4)));

// ---------------- CSR build ----------------

__global__ void init_counts_kernel(int* counts) {
    int i = blockIdx.x * blockDim.x + threadIdx.x;
    if (i < Nn) counts[i] = 1;   // self-loop
}

__global__ void count_edges_kernel(const int* __restrict__ ei, int* counts) {
    int e = blockIdx.x * blockDim.x + threadIdx.x;
    if (e < En) atomicAdd(&counts[ei[En + e]], 1);
}

enum { CHUNK = 10 };
static_assert(CHUNK * 1024 >= Nn, "scan chunk");

__global__ __launch_bounds__(1024) void scan_kernel(
    const int* __restrict__ counts, int* __restrict__ row_ptr,
    int* __restrict__ fill_ptr, float* __restrict__ dinv) {
    __shared__ int sums[1024];
    const int t = threadIdx.x;
    const int base = t * CHUNK;
    int cnt[CHUNK];
    int s = 0;
    #pragma unroll
    for (int i = 0; i < CHUNK; ++i) {
        int idx = base + i;
        int v = (idx < Nn) ? counts[idx] : 0;
        cnt[i] = v; s += v;
    }
    sums[t] = s;
    __syncthreads();
    for (int off = 1; off < 1024; off <<= 1) {
        int v = (t >= off) ? sums[t - off] : 0;
        __syncthreads();
        sums[t] += v;
        __syncthreads();
    }
    int excl = (t == 0) ? 0 : sums[t - 1];
    #pragma unroll
    for (int i = 0; i < CHUNK; ++i) {
        int idx = base + i;
        if (idx < Nn) {
            row_ptr[idx] = excl;
            fill_ptr[idx] = excl;
            dinv[idx] = rsqrtf((float)cnt[i]);
            excl += cnt[i];
        }
    }
    if (t == 1023) row_ptr[Nn] = excl;
}

__global__ void fill_kernel(const int* __restrict__ ei,
                            const float* __restrict__ dinv,
                            int* fill_ptr, int* __restrict__ col,
                            float* __restrict__ wgt) {
    int i = blockIdx.x * blockDim.x + threadIdx.x;
    if (i < Nn) {
        int p = atomicAdd(&fill_ptr[i], 1);
        col[p] = i;
        wgt[p] = dinv[i] * dinv[i];
    } else if (i < Nn + En) {
        int e = i - Nn;
        int s = ei[e];
        int d = ei[En + e];
        int p = atomicAdd(&fill_ptr[d], 1);
        col[p] = s;
        wgt[p] = dinv[s] * dinv[d];
    }
}

// ---------------- small helpers ----------------

__global__ void bsum_kernel(const float* __restrict__ a, const float* __restrict__ b,
                            float* __restrict__ out) {
    int i = blockIdx.x * blockDim.x + threadIdx.x;
    if (i < 4 * Hn) out[i] = a[i] + b[i];
}

// weight prep:
//  wihf: 512x128 f16 row-major [n][k]
//  g2wt: 128x128 f16 transposed [n][k] from g2w [k][n]
//  whf : whh in MFMA B-fragment layout [ct(32)][kt(4)][lane(64)][j(8)]
//        element (n = ct*16 + (lane&15), k = kt*32 + (lane>>4)*8 + j)
__global__ void convert_w_kernel(const float* __restrict__ wih, const float* __restrict__ whh,
                                 const float* __restrict__ g2w,
                                 _Float16* __restrict__ wihf, _Float16* __restrict__ whf,
                                 _Float16* __restrict__ g2wt) {
    int i = blockIdx.x * blockDim.x + threadIdx.x;
    if (i < 65536) {
        wihf[i] = (_Float16)wih[i];
    } else if (i < 131072) {
        int idx = i - 65536;
        int j = idx & 7, lane = (idx >> 3) & 63, kt = (idx >> 9) & 3, ct = idx >> 11;
        int n = ct * 16 + (lane & 15);
        int k = kt * 32 + (lane >> 4) * 8 + j;
        whf[idx] = (_Float16)whh[n * 128 + k];
    } else if (i < 131072 + 16384) {
        int j = i - 131072;
        int n = j >> 7, k = j & 127;
        g2wt[j] = (_Float16)g2w[k * Hn + n];
    }
}

// ---------------- GCN layer 1: aggregate x (F=5) then transform ----------------
__global__ __launch_bounds__(128) void agg_x_kernel(
    const float* __restrict__ x, const int* __restrict__ row_ptr,
    const int* __restrict__ col, const float* __restrict__ wgt,
    float* __restrict__ aggx) {
    const int n = blockIdx.x;
    const int t = threadIdx.x;
    const int s = t >> 3, f = t & 7;
    if (f >= Fin) return;
    const int start = row_ptr[n], end = row_ptr[n + 1];
    float acc = 0.f;
    for (int e = start; e < end; ++e) {
        int c = col[e];
        acc = fmaf(wgt[e], x[((size_t)s * Nn + c) * Fin + f], acc);
    }
    aggx[((size_t)s * Nn + n) * Fin + f] = acc;
}

__global__ void gemm1f_kernel(const float* __restrict__ aggx, const float* __restrict__ w,
                              const float* __restrict__ bias, _Float16* __restrict__ out) {
    int idx = blockIdx.x * blockDim.x + threadIdx.x;
    if (idx >= ROWS * Hn) return;
    int row = idx >> 7, j = idx & 127;
    const float* ar = aggx + (size_t)row * Fin;
    float s = bias[j];
    #pragma unroll
    for (int f = 0; f < Fin; ++f) s = fmaf(ar[f], w[f * Hn + j], s);
    out[idx] = (_Float16)fmaxf(s, 0.f);
}

// ---------------- GCN layer 2 aggregation, 16 B/lane gather ----------------
__global__ __launch_bounds__(256) void gcn_agg2_kernel(
    const _Float16* __restrict__ ht, const int* __restrict__ row_ptr,
    const int* __restrict__ col, const float* __restrict__ wgt,
    const float* __restrict__ bias, _Float16* __restrict__ out) {
    const int n = blockIdx.x;
    const int t = threadIdx.x;
    const int s = t >> 4;
    const int g = (t & 15) * 8;
    const int start = row_ptr[n], end = row_ptr[n + 1];
    float acc[8];
    #pragma unroll
    for (int j = 0; j < 8; ++j) acc[j] = 0.f;
    for (int e = start; e < end; ++e) {
        const int c = col[e];
        const float w = wgt[e];
        half8 v = *(const half8*)(ht + ((size_t)s * Nn + c) * Hn + g);
        #pragma unroll
        for (int j = 0; j < 8; ++j) acc[j] = fmaf(w, (float)v[j], acc[j]);
    }
    half8 o;
    #pragma unroll
    for (int j = 0; j < 8; ++j) o[j] = (_Float16)fmaxf(acc[j] + bias[g + j], 0.f);
    *(half8*)(out + ((size_t)s * Nn + n) * Hn + g) = o;
}

// ---------------- shared f16 MFMA mainloop: C = A @ B^T, K=128 ----------------
// BM=BN=128, BK=32; 4 waves, each 64x64 via 4x4 of 16x16x32. B stored [n][k].
__device__ __forceinline__ void gemm_mainloop(
    const _Float16* __restrict__ A, const _Float16* __restrict__ B,
    int M, int m0, int n0, _Float16 (*As)[40], _Float16 (*Bs)[40],
    f32x4 acc[4][4]) {
    const int tid = threadIdx.x;
    const int wave = tid >> 6;
    const int lane = tid & 63;
    const int l = lane & 15, q = lane >> 4;
    const int wm = (wave & 1) * 64, wn = (wave >> 1) * 64;
    for (int kt = 0; kt < 128; kt += 32) {
        #pragma unroll
        for (int j = 0; j < 2; ++j) {
            int idx = tid + j * 256;
            int r = idx >> 2, c = (idx & 3) * 8;
            int gr = m0 + r;
            half8 v = {0, 0, 0, 0, 0, 0, 0, 0};
            if (gr < M) v = *(const half8*)(A + (size_t)gr * 128 + kt + c);
            *(half8*)&As[r][c] = v;
            int nr = n0 + r;
            *(half8*)&Bs[r][c] = *(const half8*)(B + (size_t)nr * 128 + kt + c);
        }
        __syncthreads();
        half8 af[4], bf[4];
        #pragma unroll
        for (int i = 0; i < 4; ++i) af[i] = *(const half8*)&As[wm + i * 16 + l][q * 8];
        #pragma unroll
        for (int j = 0; j < 4; ++j) bf[j] = *(const half8*)&Bs[wn + j * 16 + l][q * 8];
        #pragma unroll
        for (int i = 0; i < 4; ++i)
            #pragma unroll
            for (int j = 0; j < 4; ++j)
                acc[i][j] = __builtin_amdgcn_mfma_f32_16x16x32_f16(
                    af[i], bf[j], acc[i][j], 0, 0, 0);
        __syncthreads();
    }
}

// Row-major output variant (Nc == 128, M % 128 == 0): LDS-staged contiguous stores.
__global__ __launch_bounds__(256) void gemm_f16_rm_kernel(
    const _Float16* __restrict__ A, const _Float16* __restrict__ B,
    _Float16* __restrict__ C, int M) {
    __shared__ _Float16 As[128][40];
    __shared__ _Float16 Bs[128][40];
    __shared__ __align__(16) _Float16 Cs[128][136];
    const int tid = threadIdx.x;
    const int m0 = blockIdx.x * 128;
    const int wave = tid >> 6, lane = tid & 63;
    const int l = lane & 15, q = lane >> 4;
    const int wm = (wave & 1) * 64, wn = (wave >> 1) * 64;
    f32x4 acc[4][4];
    #pragma unroll
    for (int i = 0; i < 4; ++i)
        #pragma unroll
        for (int j = 0; j < 4; ++j) acc[i][j] = (f32x4){0.f, 0.f, 0.f, 0.f};
    gemm_mainloop(A, B, M, m0, 0, As, Bs, acc);
    #pragma unroll
    for (int j = 0; j < 4; ++j) {
        int ccol = wn + j * 16 + l;
        #pragma unroll
        for (int i = 0; i < 4; ++i)
            #pragma unroll
            for (int r = 0; r < 4; ++r)
                Cs[wm + i * 16 + q * 4 + r][ccol] = (_Float16)acc[i][j][r];
    }
    __syncthreads();
    const size_t base = (size_t)m0 * 128;
    #pragma unroll
    for (int it = 0; it < 8; ++it) {
        int idx = it * 256 + tid;           // 0..2047
        int row = idx >> 4, ch = (idx & 15) * 8;
        *(half8*)(C + base + (size_t)row * 128 + ch) = *(const half8*)&Cs[row][ch];
    }
}

// Fragment-layout output variant for xg: out[slice][nt][ct][lane][4] f16, +bias.
// grid (4, 1250): n-block fast for A L2 reuse.
__global__ __launch_bounds__(256) void gemm_f16_xg_kernel(
    const _Float16* __restrict__ A, const _Float16* __restrict__ B,
    const float* __restrict__ bias, _Float16* __restrict__ C) {
    __shared__ _Float16 As[128][40];
    __shared__ _Float16 Bs[128][40];
    const int tid = threadIdx.x;
    const int m0 = blockIdx.y * 128;
    const int n0 = blockIdx.x * 128;
    const int wave = tid >> 6, lane = tid & 63;
    const int l = lane & 15, q = lane >> 4;
    const int wm = (wave & 1) * 64, wn = (wave >> 1) * 64;
    f32x4 acc[4][4];
    #pragma unroll
    for (int i = 0; i < 4; ++i)
        #pragma unroll
        for (int j = 0; j < 4; ++j) acc[i][j] = (f32x4){0.f, 0.f, 0.f, 0.f};
    gemm_mainloop(A, B, ROWS, m0, n0, As, Bs, acc);
    #pragma unroll
    for (int i = 0; i < 4; ++i) {
        int rt = ((m0 + wm) >> 4) + i;          // global row tile
        int slice = rt / NT_SLICE;
        int nt = rt - slice * NT_SLICE;
        #pragma unroll
        for (int j = 0; j < 4; ++j) {
            int ct = (n0 >> 4) + (wave >> 1) * 4 + j;
            int gcol = n0 + wn + j * 16 + l;
            float bv = bias[gcol];
            half4 v;
            #pragma unroll
            for (int r = 0; r < 4; ++r) v[r] = (_Float16)(acc[i][j][r] + bv);
            *(half4*)(C + ((((size_t)slice * NT_SLICE + nt) * 32 + ct) * 64 + lane) * 4) = v;
        }
    }
}

// ---------------- fused LSTM: all 8 steps in one kernel ----------------
// 512 threads = 8 waves; block owns 128 batch rows. wave (mw,nw): rows mw*64..+64,
// gate-col tiles ct = gate*8 + nw*2 + hc (h-cols nw*32..+32 for all 4 gates ->
// pointwise is wave-local). h in LDS (A-frag source), c in registers.
__global__ __launch_bounds__(512, 2) void lstm_fused_kernel(
    const _Float16* __restrict__ xg, const _Float16* __restrict__ whf,
    _Float16* __restrict__ hf) {
    __shared__ __align__(16) _Float16 h_lds[128][136];
    const int tid = threadIdx.x;
    const int wave = tid >> 6, lane = tid & 63;
    const int l = lane & 15, q = lane >> 4;
    const int mw = wave >> 2, nw = wave & 3;
    const int r_base = blockIdx.x * 128;
    float c_reg[4][2][4];
    #pragma unroll
    for (int i = 0; i < 4; ++i)
        #pragma unroll
        for (int hc = 0; hc < 2; ++hc)
            #pragma unroll
            for (int r = 0; r < 4; ++r) c_reg[i][hc][r] = 0.f;

    for (int t = 0; t < Wn; ++t) {
        f32x4 acc[4][8];
        // init acc from xg fragments
        #pragma unroll
        for (int i = 0; i < 4; ++i) {
            int grow = r_base + mw * 64 + i * 16;
            bool valid = grow < MR;
            int b = (grow >= Nn) ? 1 : 0;
            int nt = (grow - b * Nn) >> 4;
            int slice = b * Wn + t;
            size_t tbase = ((size_t)slice * NT_SLICE + nt) * 32;
            #pragma unroll
            for (int wt = 0; wt < 8; ++wt) {
                int ct = (wt >> 1) * 8 + nw * 2 + (wt & 1);
                half4 xv = {0, 0, 0, 0};
                if (valid) xv = *(const half4*)(xg + ((tbase + ct) * 64 + lane) * 4);
                acc[i][wt] = (f32x4){(float)xv[0], (float)xv[1], (float)xv[2], (float)xv[3]};
            }
        }
        if (t > 0) {
            #pragma unroll
            for (int kt = 0; kt < 4; ++kt) {
                half8 af[4];
                #pragma unroll
                for (int i = 0; i < 4; ++i)
                    af[i] = *(const half8*)&h_lds[mw * 64 + i * 16 + l][kt * 32 + q * 8];
                half8 bf[8];
                #pragma unroll
                for (int wt = 0; wt < 8; ++wt) {
                    int ct = (wt >> 1) * 8 + nw * 2 + (wt & 1);
                    bf[wt] = *(const half8*)(whf + (((size_t)ct * 4 + kt) * 64 + lane) * 8);
                }
                #pragma unroll
                for (int i = 0; i < 4; ++i)
                    #pragma unroll
                    for (int wt = 0; wt < 8; ++wt)
                        acc[i][wt] = __builtin_amdgcn_mfma_f32_16x16x32_f16(
                            af[i], bf[wt], acc[i][wt], 0, 0, 0);
            }
            __syncthreads();   // all A-reads done before h_lds overwrite
        }
        // pointwise (wave-local): gates i,f,g,o at wt = gate*2+hc
        #pragma unroll
        for (int i = 0; i < 4; ++i) {
            int row0 = mw * 64 + i * 16 + q * 4;
            #pragma unroll
            for (int hc = 0; hc < 2; ++hc) {
                int colc = nw * 32 + hc * 16 + l;
                #pragma unroll
                for (int r = 0; r < 4; ++r) {
                    float gi = acc[i][0 + hc][r];
                    float gf = acc[i][2 + hc][r];
                    float gg = acc[i][4 + hc][r];
                    float go = acc[i][6 + hc][r];
                    float si = 1.f / (1.f + __expf(-gi));
                    float sf = 1.f / (1.f + __expf(-gf));
                    float so = 1.f / (1.f + __expf(-go));
                    float tg = 2.f / (1.f + __expf(-2.f * gg)) - 1.f;
                    float cn = sf * c_reg[i][hc][r] + si * tg;
                    c_reg[i][hc][r] = cn;
                    float tc = 2.f / (1.f + __expf(-2.f * cn)) - 1.f;
                    h_lds[row0 + r][colc] = (_Float16)(so * tc);
                }
            }
        }
        __syncthreads();   // h ready for next step / final store
    }
    // final h -> global (coalesced)
    #pragma unroll
    for (int it = 0; it < 4; ++it) {
        int idx = it * 512 + tid;
        int row = idx >> 4, ch = (idx & 15) * 8;
        int grow = r_base + row;
        if (grow < MR)
            *(half8*)(hf + (size_t)grow * 128 + ch) = *(const half8*)&h_lds[row][ch];
    }
}

// ---------------- decoder ----------------
__global__ __launch_bounds__(256) void decoder_kernel(
    const _Float16* __restrict__ h, const float* __restrict__ w1,
    const float* __restrict__ b1, const float* __restrict__ w2,
    const float* __restrict__ b2, float* __restrict__ out) {
    const int wave = threadIdx.x >> 6;
    const int lane = threadIdx.x & 63;
    const int row = blockIdx.x * 4 + wave;
    if (row >= MR) return;
    const _Float16* hr = h + (size_t)row * Hn;
    float d = b1[lane];
    #pragma unroll 8
    for (int k = 0; k < Hn; ++k) d = fmaf((float)hr[k], w1[k * 64 + lane], d);
    d = fmaxf(d, 0.f);
    float p = d * w2[lane];
    #pragma unroll
    for (int off = 32; off; off >>= 1) p += __shfl_down(p, off);
    if (lane == 0) out[row] = p + b2[0];
}

// ---------------- launch ----------------

extern "C" void kernel_launch(void* const* d_in, const int* in_sizes, int n_in,
                              void* d_out, int out_size, void* d_ws, size_t ws_size,
                              hipStream_t stream) {
    const float* x   = (const float*)d_in[0];
    const int*   ei  = (const int*)d_in[1];
    const float* g1w = (const float*)d_in[2];
    const float* g1b = (const float*)d_in[3];
    const float* g2w = (const float*)d_in[4];
    const float* g2b = (const float*)d_in[5];
    const float* wih = (const float*)d_in[6];
    const float* whh = (const float*)d_in[7];
    const float* bih = (const float*)d_in[8];
    const float* bhh = (const float*)d_in[9];
    const float* dw1 = (const float*)d_in[10];
    const float* db1 = (const float*)d_in[11];
    const float* dw2 = (const float*)d_in[12];
    const float* db2 = (const float*)d_in[13];
    float* out = (float*)d_out;

    char* p = (char*)d_ws;
    auto alloc = [&](size_t bytes) {
        char* r = p;
        p += (bytes + 255) & ~(size_t)255;
        return r;
    };
    int*      counts   = (int*)     alloc(Nn * 4);
    int*      row_ptr  = (int*)     alloc((Nn + 1) * 4);
    int*      fill_ptr = (int*)     alloc((Nn + 1) * 4);
    float*    dinv     = (float*)   alloc(Nn * 4);
    float*    bsum     = (float*)   alloc(4 * Hn * 4);
    int*      col      = (int*)     alloc((En + Nn) * 4);
    float*    wgt      = (float*)   alloc((En + Nn) * 4);
    _Float16* wihf     = (_Float16*)alloc(512 * 128 * 2);
    _Float16* whf      = (_Float16*)alloc(512 * 128 * 2);
    _Float16* g2wt     = (_Float16*)alloc(128 * 128 * 2);
    float*    aggx     = (float*)   alloc((size_t)ROWS * Fin * 4);    // 3.2 MB
    _Float16* h2f      = (_Float16*)alloc((size_t)ROWS * Hn * 2);     // 41 MB
    _Float16* hf       = (_Float16*)alloc((size_t)MR * Hn * 2);       // 5.1 MB
    // xg (164 MB, fragment layout) aliases h1f/htf (dead before xg is written)
    _Float16* xg       = (_Float16*)alloc((size_t)ROWS * 4 * Hn * 2); // 164 MB
    _Float16* h1f      = xg;
    _Float16* htf      = xg + (size_t)ROWS * Hn;

    // ---- CSR build + weight prep ----
    init_counts_kernel<<<(Nn + 255) / 256, 256, 0, stream>>>(counts);
    count_edges_kernel<<<(En + 255) / 256, 256, 0, stream>>>(ei, counts);
    scan_kernel<<<1, 1024, 0, stream>>>(counts, row_ptr, fill_ptr, dinv);
    fill_kernel<<<(Nn + En + 255) / 256, 256, 0, stream>>>(ei, dinv, fill_ptr, col, wgt);
    bsum_kernel<<<(4 * Hn + 255) / 256, 256, 0, stream>>>(bih, bhh, bsum);
    convert_w_kernel<<<(131072 + 16384 + 255) / 256, 256, 0, stream>>>(
        wih, whh, g2w, wihf, whf, g2wt);

    // ---- GCN layer 1: aggregate (F=5) then transform ----
    agg_x_kernel<<<Nn, 128, 0, stream>>>(x, row_ptr, col, wgt, aggx);
    gemm1f_kernel<<<(ROWS * Hn + 255) / 256, 256, 0, stream>>>(aggx, g1w, g1b, h1f);

    // ---- GCN layer 2: transform (MFMA) then aggregate ----
    gemm_f16_rm_kernel<<<ROWS / 128, 256, 0, stream>>>(h1f, g2wt, htf, ROWS);
    gcn_agg2_kernel<<<Nn, 256, 0, stream>>>(htf, row_ptr, col, wgt, g2b, h2f);

    // ---- LSTM x-part, fragment layout (+combined bias) ----
    gemm_f16_xg_kernel<<<dim3(4, ROWS / 128), 256, 0, stream>>>(h2f, wihf, bsum, xg);

    // ---- fused 8-step LSTM ----
    lstm_fused_kernel<<<(MR + 127) / 128, 512, 0, stream>>>(xg, whf, hf);

    // ---- decoder ----
    decoder_kernel<<<(MR + 3) / 4, 256, 0, stream>>>(hf, dw1, db1, dw2, db2, out);
}

// Round 5
// 360.564 us; speedup vs baseline: 2.0586x; 1.3032x over previous
//
#include <hip/hip_runtime.h>
#include <hip/hip_fp16.h>
#include <cstdint>
#include <cstddef>

// Problem constants (match reference)
#define Bn   2
#define Wn   8
#define Nn   10000
#define Fin  5
#define En   80000
#define Hn   128
#define BWn  (Bn*Wn)        // 16
#define ROWS (BWn*Nn)       // 160000
#define MR   (Bn*Nn)        // 20000  (LSTM batch rows)
#define LROWS 32            // LSTM rows per block: MR/32 = 625 blocks exactly

typedef _Float16 half8 __attribute__((ext_vector_type(8)));
typedef float f32x4 __attribute__((ext_vector_type(4)));

// ---------------- CSR build ----------------

__global__ void init_counts_kernel(int* counts) {
    int i = blockIdx.x * blockDim.x + threadIdx.x;
    if (i < Nn) counts[i] = 1;   // self-loop
}

__global__ void count_edges_kernel(const int* __restrict__ ei, int* counts) {
    int e = blockIdx.x * blockDim.x + threadIdx.x;
    if (e < En) atomicAdd(&counts[ei[En + e]], 1);
}

enum { CHUNK = 10 };
static_assert(CHUNK * 1024 >= Nn, "scan chunk");

__global__ __launch_bounds__(1024) void scan_kernel(
    const int* __restrict__ counts, int* __restrict__ row_ptr,
    int* __restrict__ fill_ptr, float* __restrict__ dinv) {
    __shared__ int sums[1024];
    const int t = threadIdx.x;
    const int base = t * CHUNK;
    int cnt[CHUNK];
    int s = 0;
    #pragma unroll
    for (int i = 0; i < CHUNK; ++i) {
        int idx = base + i;
        int v = (idx < Nn) ? counts[idx] : 0;
        cnt[i] = v; s += v;
    }
    sums[t] = s;
    __syncthreads();
    for (int off = 1; off < 1024; off <<= 1) {
        int v = (t >= off) ? sums[t - off] : 0;
        __syncthreads();
        sums[t] += v;
        __syncthreads();
    }
    int excl = (t == 0) ? 0 : sums[t - 1];
    #pragma unroll
    for (int i = 0; i < CHUNK; ++i) {
        int idx = base + i;
        if (idx < Nn) {
            row_ptr[idx] = excl;
            fill_ptr[idx] = excl;
            dinv[idx] = rsqrtf((float)cnt[i]);
            excl += cnt[i];
        }
    }
    if (t == 1023) row_ptr[Nn] = excl;
}

__global__ void fill_kernel(const int* __restrict__ ei,
                            const float* __restrict__ dinv,
                            int* fill_ptr, int* __restrict__ col,
                            float* __restrict__ wgt) {
    int i = blockIdx.x * blockDim.x + threadIdx.x;
    if (i < Nn) {
        int p = atomicAdd(&fill_ptr[i], 1);
        col[p] = i;
        wgt[p] = dinv[i] * dinv[i];
    } else if (i < Nn + En) {
        int e = i - Nn;
        int s = ei[e];
        int d = ei[En + e];
        int p = atomicAdd(&fill_ptr[d], 1);
        col[p] = s;
        wgt[p] = dinv[s] * dinv[d];
    }
}

// ---------------- small helpers ----------------

__global__ void bsum_kernel(const float* __restrict__ a, const float* __restrict__ b,
                            float* __restrict__ out) {
    int i = blockIdx.x * blockDim.x + threadIdx.x;
    if (i < 4 * Hn) out[i] = a[i] + b[i];
}

// weight prep:
//  wif/whf: wih/whh (512x128, [n][k]) in MFMA B-fragment layout
//           [ct(32)][kt(4)][lane(64)][j(8)]; element (n = ct*16 + (lane&15),
//           k = kt*32 + (lane>>4)*8 + j)
//  g2wt: 128x128 f16 transposed [n][k] from g2w [k][n]
__global__ void convert_w_kernel(const float* __restrict__ wih, const float* __restrict__ whh,
                                 const float* __restrict__ g2w,
                                 _Float16* __restrict__ wif, _Float16* __restrict__ whf,
                                 _Float16* __restrict__ g2wt) {
    int i = blockIdx.x * blockDim.x + threadIdx.x;
    if (i < 131072) {
        int idx = i & 65535;
        int j = idx & 7, lane = (idx >> 3) & 63, kt = (idx >> 9) & 3, ct = idx >> 11;
        int n = ct * 16 + (lane & 15);
        int k = kt * 32 + (lane >> 4) * 8 + j;
        if (i < 65536) wif[idx] = (_Float16)wih[n * 128 + k];
        else           whf[idx] = (_Float16)whh[n * 128 + k];
    } else if (i < 131072 + 16384) {
        int j = i - 131072;
        int n = j >> 7, k = j & 127;
        g2wt[j] = (_Float16)g2w[k * Hn + n];
    }
}

// ---------------- GCN layer 1: aggregate x (F=5) then transform ----------------
__global__ __launch_bounds__(128) void agg_x_kernel(
    const float* __restrict__ x, const int* __restrict__ row_ptr,
    const int* __restrict__ col, const float* __restrict__ wgt,
    float* __restrict__ aggx) {
    const int n = blockIdx.x;
    const int t = threadIdx.x;
    const int s = t >> 3, f = t & 7;
    if (f >= Fin) return;
    const int start = row_ptr[n], end = row_ptr[n + 1];
    float acc = 0.f;
    for (int e = start; e < end; ++e) {
        int c = col[e];
        acc = fmaf(wgt[e], x[((size_t)s * Nn + c) * Fin + f], acc);
    }
    aggx[((size_t)s * Nn + n) * Fin + f] = acc;
}

__global__ void gemm1f_kernel(const float* __restrict__ aggx, const float* __restrict__ w,
                              const float* __restrict__ bias, _Float16* __restrict__ out) {
    int idx = blockIdx.x * blockDim.x + threadIdx.x;
    if (idx >= ROWS * Hn) return;
    int row = idx >> 7, j = idx & 127;
    const float* ar = aggx + (size_t)row * Fin;
    float s = bias[j];
    #pragma unroll
    for (int f = 0; f < Fin; ++f) s = fmaf(ar[f], w[f * Hn + j], s);
    out[idx] = (_Float16)fmaxf(s, 0.f);
}

// ---------------- GCN layer 2 aggregation, 16 B/lane gather ----------------
__global__ __launch_bounds__(256) void gcn_agg2_kernel(
    const _Float16* __restrict__ ht, const int* __restrict__ row_ptr,
    const int* __restrict__ col, const float* __restrict__ wgt,
    const float* __restrict__ bias, _Float16* __restrict__ out) {
    const int n = blockIdx.x;
    const int t = threadIdx.x;
    const int s = t >> 4;
    const int g = (t & 15) * 8;
    const int start = row_ptr[n], end = row_ptr[n + 1];
    float acc[8];
    #pragma unroll
    for (int j = 0; j < 8; ++j) acc[j] = 0.f;
    for (int e = start; e < end; ++e) {
        const int c = col[e];
        const float w = wgt[e];
        half8 v = *(const half8*)(ht + ((size_t)s * Nn + c) * Hn + g);
        #pragma unroll
        for (int j = 0; j < 8; ++j) acc[j] = fmaf(w, (float)v[j], acc[j]);
    }
    half8 o;
    #pragma unroll
    for (int j = 0; j < 8; ++j) o[j] = (_Float16)fmaxf(acc[j] + bias[g + j], 0.f);
    *(half8*)(out + ((size_t)s * Nn + n) * Hn + g) = o;
}

// ---------------- f16 MFMA GEMM (row-major out, Nc=128): C = A @ B^T ----------------
__global__ __launch_bounds__(256) void gemm_f16_rm_kernel(
    const _Float16* __restrict__ A, const _Float16* __restrict__ B,
    _Float16* __restrict__ C, int M) {
    __shared__ _Float16 As[128][40];
    __shared__ _Float16 Bs[128][40];
    __shared__ __align__(16) _Float16 Cs[128][136];
    const int tid = threadIdx.x;
    const int m0 = blockIdx.x * 128;
    const int wave = tid >> 6, lane = tid & 63;
    const int l = lane & 15, q = lane >> 4;
    const int wm = (wave & 1) * 64, wn = (wave >> 1) * 64;
    f32x4 acc[4][4];
    #pragma unroll
    for (int i = 0; i < 4; ++i)
        #pragma unroll
        for (int j = 0; j < 4; ++j) acc[i][j] = (f32x4){0.f, 0.f, 0.f, 0.f};
    for (int kt = 0; kt < 128; kt += 32) {
        #pragma unroll
        for (int j = 0; j < 2; ++j) {
            int idx = tid + j * 256;
            int r = idx >> 2, c = (idx & 3) * 8;
            int gr = m0 + r;
            half8 v = {0, 0, 0, 0, 0, 0, 0, 0};
            if (gr < M) v = *(const half8*)(A + (size_t)gr * 128 + kt + c);
            *(half8*)&As[r][c] = v;
            *(half8*)&Bs[r][c] = *(const half8*)(B + (size_t)r * 128 + kt + c);
        }
        __syncthreads();
        half8 af[4], bf[4];
        #pragma unroll
        for (int i = 0; i < 4; ++i) af[i] = *(const half8*)&As[wm + i * 16 + l][q * 8];
        #pragma unroll
        for (int j = 0; j < 4; ++j) bf[j] = *(const half8*)&Bs[wn + j * 16 + l][q * 8];
        #pragma unroll
        for (int i = 0; i < 4; ++i)
            #pragma unroll
            for (int j = 0; j < 4; ++j)
                acc[i][j] = __builtin_amdgcn_mfma_f32_16x16x32_f16(
                    af[i], bf[j], acc[i][j], 0, 0, 0);
        __syncthreads();
    }
    #pragma unroll
    for (int j = 0; j < 4; ++j) {
        int ccol = wn + j * 16 + l;
        #pragma unroll
        for (int i = 0; i < 4; ++i)
            #pragma unroll
            for (int r = 0; r < 4; ++r)
                Cs[wm + i * 16 + q * 4 + r][ccol] = (_Float16)acc[i][j][r];
    }
    __syncthreads();
    const size_t base = (size_t)m0 * 128;
    #pragma unroll
    for (int it = 0; it < 8; ++it) {
        int idx = it * 256 + tid;
        int row = idx >> 4, ch = (idx & 15) * 8;
        *(half8*)(C + base + (size_t)row * 128 + ch) = *(const half8*)&Cs[row][ch];
    }
}

// ---------------- fully fused LSTM: x-part + h-part + pointwise, all 8 steps ----------------
// grid 625 x 512 threads (8 waves); block owns 32 rows (exact: 625*32 = MR).
// Wave nw owns h-cols nw*16..+15 for ALL 4 gates (ct = g*8+nw) -> pointwise wave-local.
// W_ih and W_hh register-cached in B-frag layout (loaded once). x tile double-buffered
// in LDS with register prefetch one full step ahead. h in LDS (A-frag source), c in regs.
__global__ __launch_bounds__(512, 1) void lstm_fused2_kernel(
    const _Float16* __restrict__ h2, const _Float16* __restrict__ wif,
    const _Float16* __restrict__ whf, const float* __restrict__ bsum,
    _Float16* __restrict__ hf) {
    __shared__ __align__(16) _Float16 x_lds[2][LROWS][144];
    __shared__ __align__(16) _Float16 h_lds[LROWS][144];
    const int tid = threadIdx.x;
    const int nw = tid >> 6, lane = tid & 63;
    const int l = lane & 15, q = lane >> 4;
    const int r0 = blockIdx.x * LROWS;
    // staging coords: 512 threads = 32 rows x 16 half8-chunks
    const int srow = tid >> 4, sch = (tid & 15) * 8;
    const int sgrow = r0 + srow;
    const int sb = (sgrow >= Nn) ? 1 : 0;
    const int sn = sgrow - sb * Nn;

    // register-cache both weight matrices in B-frag layout: [gate][kt]
    half8 wic[4][4], whc[4][4];
    #pragma unroll
    for (int g = 0; g < 4; ++g) {
        int ct = g * 8 + nw;
        #pragma unroll
        for (int kt = 0; kt < 4; ++kt) {
            wic[g][kt] = *(const half8*)(wif + (((size_t)ct * 4 + kt) * 64 + lane) * 8);
            whc[g][kt] = *(const half8*)(whf + (((size_t)ct * 4 + kt) * 64 + lane) * 8);
        }
    }
    float bias[4];
    #pragma unroll
    for (int g = 0; g < 4; ++g) bias[g] = bsum[g * 128 + nw * 16 + l];
    float c_reg[2][4];
    #pragma unroll
    for (int i = 0; i < 2; ++i)
        #pragma unroll
        for (int r = 0; r < 4; ++r) c_reg[i][r] = 0.f;

    // preload x_0
    *(half8*)&x_lds[0][srow][sch] =
        *(const half8*)(h2 + ((size_t)(sb * Wn) * Nn + sn) * 128 + sch);
    __syncthreads();

    for (int t = 0; t < Wn; ++t) {
        // prefetch x_{t+1} into registers (latency hidden behind this step's MFMA)
        half8 xv = {0, 0, 0, 0, 0, 0, 0, 0};
        if (t + 1 < Wn)
            xv = *(const half8*)(h2 + ((size_t)(sb * Wn + t + 1) * Nn + sn) * 128 + sch);

        f32x4 acc[2][4];
        #pragma unroll
        for (int i = 0; i < 2; ++i)
            #pragma unroll
            for (int g = 0; g < 4; ++g)
                acc[i][g] = (f32x4){bias[g], bias[g], bias[g], bias[g]};

        // x-pass: gates += x_t @ W_ih^T
        #pragma unroll
        for (int kt = 0; kt < 4; ++kt) {
            half8 af[2];
            #pragma unroll
            for (int i = 0; i < 2; ++i)
                af[i] = *(const half8*)&x_lds[t & 1][i * 16 + l][kt * 32 + q * 8];
            #pragma unroll
            for (int i = 0; i < 2; ++i)
                #pragma unroll
                for (int g = 0; g < 4; ++g)
                    acc[i][g] = __builtin_amdgcn_mfma_f32_16x16x32_f16(
                        af[i], wic[g][kt], acc[i][g], 0, 0, 0);
        }
        // h-pass: gates += h_{t-1} @ W_hh^T
        if (t > 0) {
            #pragma unroll
            for (int kt = 0; kt < 4; ++kt) {
                half8 af[2];
                #pragma unroll
                for (int i = 0; i < 2; ++i)
                    af[i] = *(const half8*)&h_lds[i * 16 + l][kt * 32 + q * 8];
                #pragma unroll
                for (int i = 0; i < 2; ++i)
                    #pragma unroll
                    for (int g = 0; g < 4; ++g)
                        acc[i][g] = __builtin_amdgcn_mfma_f32_16x16x32_f16(
                            af[i], whc[g][kt], acc[i][g], 0, 0, 0);
            }
        }
        __syncthreads();   // all x_lds/h_lds reads done

        // pointwise (wave-local) -> h_lds; stage x_{t+1} -> other x_lds buffer
        #pragma unroll
        for (int i = 0; i < 2; ++i) {
            #pragma unroll
            for (int r = 0; r < 4; ++r) {
                float gi = acc[i][0][r];
                float gf = acc[i][1][r];
                float gg = acc[i][2][r];
                float go = acc[i][3][r];
                float si = 1.f / (1.f + __expf(-gi));
                float sf = 1.f / (1.f + __expf(-gf));
                float so = 1.f / (1.f + __expf(-go));
                float tg = 2.f / (1.f + __expf(-2.f * gg)) - 1.f;
                float cn = sf * c_reg[i][r] + si * tg;
                c_reg[i][r] = cn;
                float tc = 2.f / (1.f + __expf(-2.f * cn)) - 1.f;
                h_lds[i * 16 + q * 4 + r][nw * 16 + l] = (_Float16)(so * tc);
            }
        }
        if (t + 1 < Wn) *(half8*)&x_lds[(t + 1) & 1][srow][sch] = xv;
        __syncthreads();   // h_lds / x_lds ready for next step
    }
    // final h -> global (coalesced half8)
    *(half8*)(hf + (size_t)sgrow * 128 + sch) = *(const half8*)&h_lds[srow][sch];
}

// ---------------- decoder ----------------
__global__ __launch_bounds__(256) void decoder_kernel(
    const _Float16* __restrict__ h, const float* __restrict__ w1,
    const float* __restrict__ b1, const float* __restrict__ w2,
    const float* __restrict__ b2, float* __restrict__ out) {
    const int wave = threadIdx.x >> 6;
    const int lane = threadIdx.x & 63;
    const int row = blockIdx.x * 4 + wave;
    if (row >= MR) return;
    const _Float16* hr = h + (size_t)row * Hn;
    float d = b1[lane];
    #pragma unroll 8
    for (int k = 0; k < Hn; ++k) d = fmaf((float)hr[k], w1[k * 64 + lane], d);
    d = fmaxf(d, 0.f);
    float p = d * w2[lane];
    #pragma unroll
    for (int off = 32; off; off >>= 1) p += __shfl_down(p, off);
    if (lane == 0) out[row] = p + b2[0];
}

// ---------------- launch ----------------

extern "C" void kernel_launch(void* const* d_in, const int* in_sizes, int n_in,
                              void* d_out, int out_size, void* d_ws, size_t ws_size,
                              hipStream_t stream) {
    const float* x   = (const float*)d_in[0];
    const int*   ei  = (const int*)d_in[1];
    const float* g1w = (const float*)d_in[2];
    const float* g1b = (const float*)d_in[3];
    const float* g2w = (const float*)d_in[4];
    const float* g2b = (const float*)d_in[5];
    const float* wih = (const float*)d_in[6];
    const float* whh = (const float*)d_in[7];
    const float* bih = (const float*)d_in[8];
    const float* bhh = (const float*)d_in[9];
    const float* dw1 = (const float*)d_in[10];
    const float* db1 = (const float*)d_in[11];
    const float* dw2 = (const float*)d_in[12];
    const float* db2 = (const float*)d_in[13];
    float* out = (float*)d_out;

    char* p = (char*)d_ws;
    auto alloc = [&](size_t bytes) {
        char* r = p;
        p += (bytes + 255) & ~(size_t)255;
        return r;
    };
    int*      counts   = (int*)     alloc(Nn * 4);
    int*      row_ptr  = (int*)     alloc((Nn + 1) * 4);
    int*      fill_ptr = (int*)     alloc((Nn + 1) * 4);
    float*    dinv     = (float*)   alloc(Nn * 4);
    float*    bsum     = (float*)   alloc(4 * Hn * 4);
    int*      col      = (int*)     alloc((En + Nn) * 4);
    float*    wgt      = (float*)   alloc((En + Nn) * 4);
    _Float16* wif      = (_Float16*)alloc(512 * 128 * 2);
    _Float16* whf      = (_Float16*)alloc(512 * 128 * 2);
    _Float16* g2wt     = (_Float16*)alloc(128 * 128 * 2);
    float*    aggx     = (float*)   alloc((size_t)ROWS * Fin * 4);    // 3.2 MB
    _Float16* h1f      = (_Float16*)alloc((size_t)ROWS * Hn * 2);     // 41 MB
    _Float16* htf      = (_Float16*)alloc((size_t)ROWS * Hn * 2);     // 41 MB
    _Float16* h2f      = (_Float16*)alloc((size_t)ROWS * Hn * 2);     // 41 MB
    _Float16* hf       = (_Float16*)alloc((size_t)MR * Hn * 2);       // 5.1 MB

    // ---- CSR build + weight prep ----
    init_counts_kernel<<<(Nn + 255) / 256, 256, 0, stream>>>(counts);
    count_edges_kernel<<<(En + 255) / 256, 256, 0, stream>>>(ei, counts);
    scan_kernel<<<1, 1024, 0, stream>>>(counts, row_ptr, fill_ptr, dinv);
    fill_kernel<<<(Nn + En + 255) / 256, 256, 0, stream>>>(ei, dinv, fill_ptr, col, wgt);
    bsum_kernel<<<(4 * Hn + 255) / 256, 256, 0, stream>>>(bih, bhh, bsum);
    convert_w_kernel<<<(131072 + 16384 + 255) / 256, 256, 0, stream>>>(
        wih, whh, g2w, wif, whf, g2wt);

    // ---- GCN layer 1: aggregate (F=5) then transform ----
    agg_x_kernel<<<Nn, 128, 0, stream>>>(x, row_ptr, col, wgt, aggx);
    gemm1f_kernel<<<(ROWS * Hn + 255) / 256, 256, 0, stream>>>(aggx, g1w, g1b, h1f);

    // ---- GCN layer 2: transform (MFMA) then aggregate ----
    gemm_f16_rm_kernel<<<ROWS / 128, 256, 0, stream>>>(h1f, g2wt, htf, ROWS);
    gcn_agg2_kernel<<<Nn, 256, 0, stream>>>(htf, row_ptr, col, wgt, g2b, h2f);

    // ---- fully fused LSTM (x-part + recurrence + pointwise, all 8 steps) ----
    lstm_fused2_kernel<<<MR / LROWS, 512, 0, stream>>>(h2f, wif, whf, bsum, hf);

    // ---- decoder ----
    decoder_kernel<<<(MR + 3) / 4, 256, 0, stream>>>(hf, dw1, db1, dw2, db2, out);
}

// Round 6
// 281.699 us; speedup vs baseline: 2.6350x; 1.2800x over previous
//
#include <hip/hip_runtime.h>
#include <hip/hip_fp16.h>
#include <cstdint>
#include <cstddef>

// Problem constants (match reference)
#define Bn   2
#define Wn   8
#define Nn   10000
#define Fin  5
#define En   80000
#define Hn   128
#define BWn  (Bn*Wn)        // 16
#define ROWS (BWn*Nn)       // 160000
#define MR   (Bn*Nn)        // 20000  (LSTM batch rows)
#define LROWS 32            // LSTM rows per block: MR/32 = 625 blocks exactly

typedef _Float16 half8 __attribute__((ext_vector_type(8)));
typedef float f32x4 __attribute__((ext_vector_type(4)));

#define LOG2E 1.44269504088896f

__device__ __forceinline__ float fast_sigmoid(float x) {
    // 1/(1+exp(-x)) via v_exp_f32 + v_rcp_f32 (~1e-6 rel; threshold is 2.9e-5 abs)
    return __builtin_amdgcn_rcpf(1.f + __builtin_amdgcn_exp2f(-LOG2E * x));
}
__device__ __forceinline__ float fast_tanh(float x) {
    // tanh(x) = 1 - 2/(1+exp(2x))
    return fmaf(-2.f, __builtin_amdgcn_rcpf(1.f + __builtin_amdgcn_exp2f(2.f * LOG2E * x)), 1.f);
}

// ---------------- CSR build ----------------

__global__ void init_counts_kernel(int* counts) {
    int i = blockIdx.x * blockDim.x + threadIdx.x;
    if (i < Nn) counts[i] = 1;   // self-loop
}

__global__ void count_edges_kernel(const int* __restrict__ ei, int* counts) {
    int e = blockIdx.x * blockDim.x + threadIdx.x;
    if (e < En) atomicAdd(&counts[ei[En + e]], 1);
}

enum { CHUNK = 10 };
static_assert(CHUNK * 1024 >= Nn, "scan chunk");

__global__ __launch_bounds__(1024) void scan_kernel(
    const int* __restrict__ counts, int* __restrict__ row_ptr,
    int* __restrict__ fill_ptr, float* __restrict__ dinv) {
    __shared__ int sums[1024];
    const int t = threadIdx.x;
    const int base = t * CHUNK;
    int cnt[CHUNK];
    int s = 0;
    #pragma unroll
    for (int i = 0; i < CHUNK; ++i) {
        int idx = base + i;
        int v = (idx < Nn) ? counts[idx] : 0;
        cnt[i] = v; s += v;
    }
    sums[t] = s;
    __syncthreads();
    for (int off = 1; off < 1024; off <<= 1) {
        int v = (t >= off) ? sums[t - off] : 0;
        __syncthreads();
        sums[t] += v;
        __syncthreads();
    }
    int excl = (t == 0) ? 0 : sums[t - 1];
    #pragma unroll
    for (int i = 0; i < CHUNK; ++i) {
        int idx = base + i;
        if (idx < Nn) {
            row_ptr[idx] = excl;
            fill_ptr[idx] = excl;
            dinv[idx] = rsqrtf((float)cnt[i]);
            excl += cnt[i];
        }
    }
    if (t == 1023) row_ptr[Nn] = excl;
}

__global__ void fill_kernel(const int* __restrict__ ei,
                            const float* __restrict__ dinv,
                            int* fill_ptr, int* __restrict__ col,
                            float* __restrict__ wgt) {
    int i = blockIdx.x * blockDim.x + threadIdx.x;
    if (i < Nn) {
        int p = atomicAdd(&fill_ptr[i], 1);
        col[p] = i;
        wgt[p] = dinv[i] * dinv[i];
    } else if (i < Nn + En) {
        int e = i - Nn;
        int s = ei[e];
        int d = ei[En + e];
        int p = atomicAdd(&fill_ptr[d], 1);
        col[p] = s;
        wgt[p] = dinv[s] * dinv[d];
    }
}

// ---------------- small helpers ----------------

__global__ void bsum_kernel(const float* __restrict__ a, const float* __restrict__ b,
                            float* __restrict__ out) {
    int i = blockIdx.x * blockDim.x + threadIdx.x;
    if (i < 4 * Hn) out[i] = a[i] + b[i];
}

// weight prep:
//  wif/whf: wih/whh (512x128, [n][k]) in MFMA B-fragment layout
//           [ct(32)][kt(4)][lane(64)][j(8)]; element (n = ct*16 + (lane&15),
//           k = kt*32 + (lane>>4)*8 + j)
//  g2wt: 128x128 f16 transposed [n][k] from g2w [k][n]
__global__ void convert_w_kernel(const float* __restrict__ wih, const float* __restrict__ whh,
                                 const float* __restrict__ g2w,
                                 _Float16* __restrict__ wif, _Float16* __restrict__ whf,
                                 _Float16* __restrict__ g2wt) {
    int i = blockIdx.x * blockDim.x + threadIdx.x;
    if (i < 131072) {
        int idx = i & 65535;
        int j = idx & 7, lane = (idx >> 3) & 63, kt = (idx >> 9) & 3, ct = idx >> 11;
        int n = ct * 16 + (lane & 15);
        int k = kt * 32 + (lane >> 4) * 8 + j;
        if (i < 65536) wif[idx] = (_Float16)wih[n * 128 + k];
        else           whf[idx] = (_Float16)whh[n * 128 + k];
    } else if (i < 131072 + 16384) {
        int j = i - 131072;
        int n = j >> 7, k = j & 127;
        g2wt[j] = (_Float16)g2w[k * Hn + n];
    }
}

// ---------------- GCN layer 1 aggregation (F=5), output in (n,s) row order ----------------
__global__ __launch_bounds__(128) void agg_x_kernel(
    const float* __restrict__ x, const int* __restrict__ row_ptr,
    const int* __restrict__ col, const float* __restrict__ wgt,
    float* __restrict__ aggx) {
    const int n = blockIdx.x;
    const int t = threadIdx.x;
    const int s = t >> 3, f = t & 7;
    if (f >= Fin) return;
    const int start = row_ptr[n], end = row_ptr[n + 1];
    float acc = 0.f;
    for (int e = start; e < end; ++e) {
        int c = col[e];
        acc = fmaf(wgt[e], x[((size_t)s * Nn + c) * Fin + f], acc);
    }
    aggx[((size_t)n * BWn + s) * Fin + f] = acc;   // (n,s) order
}

// ---------------- fused GCN2: h1 = relu(aggx@W1+b1) in-reg, ht = h1 @ g2w (MFMA) ----------
// rows in (n,s) order. grid 1250 x 256 threads.
__global__ __launch_bounds__(256) void gcn2_fused_kernel(
    const float* __restrict__ aggx, const float* __restrict__ w1,
    const float* __restrict__ b1, const _Float16* __restrict__ g2wt,
    _Float16* __restrict__ C) {
    __shared__ __align__(16) _Float16 s_buf[128][136];   // A tile (K=128), reused as C stage
    __shared__ _Float16 Bs[128][40];
    const int tid = threadIdx.x;
    const int m0 = blockIdx.x * 128;
    // ---- phase 1: h1 microtile 8 rows x 8 cols per thread ----
    {
        const int rg = tid >> 4;            // 16 row-groups of 8
        const int cg = tid & 15;            // 16 col-groups of 8
        float wreg[Fin][8], breg[8];
        #pragma unroll
        for (int k = 0; k < 8; ++k) breg[k] = b1[cg * 8 + k];
        #pragma unroll
        for (int f = 0; f < Fin; ++f)
            #pragma unroll
            for (int k = 0; k < 8; ++k) wreg[f][k] = w1[f * Hn + cg * 8 + k];
        #pragma unroll
        for (int rr = 0; rr < 8; ++rr) {
            const float* ar = aggx + (size_t)(m0 + rg * 8 + rr) * Fin;
            float a[Fin];
            #pragma unroll
            for (int f = 0; f < Fin; ++f) a[f] = ar[f];
            half8 v;
            #pragma unroll
            for (int k = 0; k < 8; ++k) {
                float s = breg[k];
                #pragma unroll
                for (int f = 0; f < Fin; ++f) s = fmaf(a[f], wreg[f][k], s);
                v[k] = (_Float16)fmaxf(s, 0.f);
            }
            *(half8*)&s_buf[rg * 8 + rr][cg * 8] = v;
        }
    }
    __syncthreads();
    // ---- phase 2: MFMA vs g2wt, A resident in s_buf ----
    const int wave = tid >> 6, lane = tid & 63;
    const int l = lane & 15, q = lane >> 4;
    const int wm = (wave & 1) * 64, wn = (wave >> 1) * 64;
    f32x4 acc[4][4];
    #pragma unroll
    for (int i = 0; i < 4; ++i)
        #pragma unroll
        for (int j = 0; j < 4; ++j) acc[i][j] = (f32x4){0.f, 0.f, 0.f, 0.f};
    for (int kt = 0; kt < 128; kt += 32) {
        #pragma unroll
        for (int j = 0; j < 2; ++j) {
            int idx = tid + j * 256;
            int r = idx >> 2, c = (idx & 3) * 8;
            *(half8*)&Bs[r][c] = *(const half8*)(g2wt + (size_t)r * 128 + kt + c);
        }
        __syncthreads();
        half8 af[4], bf[4];
        #pragma unroll
        for (int i = 0; i < 4; ++i) af[i] = *(const half8*)&s_buf[wm + i * 16 + l][kt + q * 8];
        #pragma unroll
        for (int j = 0; j < 4; ++j) bf[j] = *(const half8*)&Bs[wn + j * 16 + l][q * 8];
        #pragma unroll
        for (int i = 0; i < 4; ++i)
            #pragma unroll
            for (int j = 0; j < 4; ++j)
                acc[i][j] = __builtin_amdgcn_mfma_f32_16x16x32_f16(
                    af[i], bf[j], acc[i][j], 0, 0, 0);
        __syncthreads();
    }
    // ---- phase 3: stage C through s_buf (A tile dead), contiguous stores ----
    #pragma unroll
    for (int j = 0; j < 4; ++j) {
        int ccol = wn + j * 16 + l;
        #pragma unroll
        for (int i = 0; i < 4; ++i)
            #pragma unroll
            for (int r = 0; r < 4; ++r)
                s_buf[wm + i * 16 + q * 4 + r][ccol] = (_Float16)acc[i][j][r];
    }
    __syncthreads();
    const size_t base = (size_t)m0 * 128;
    #pragma unroll
    for (int it = 0; it < 8; ++it) {
        int idx = it * 256 + tid;
        int row = idx >> 4, ch = (idx & 15) * 8;
        *(half8*)(C + base + (size_t)row * 128 + ch) = *(const half8*)&s_buf[row][ch];
    }
}

// ---------------- GCN layer 2 aggregation: contiguous 4 KB per edge ((n,s) order) --------
__global__ __launch_bounds__(256) void gcn_agg2_kernel(
    const _Float16* __restrict__ ht, const int* __restrict__ row_ptr,
    const int* __restrict__ col, const float* __restrict__ wgt,
    const float* __restrict__ bias, _Float16* __restrict__ out) {
    const int n = blockIdx.x;
    const int t = threadIdx.x;
    const int s = t >> 4;
    const int g = (t & 15) * 8;
    const int start = row_ptr[n], end = row_ptr[n + 1];
    float acc[8];
    #pragma unroll
    for (int j = 0; j < 8; ++j) acc[j] = 0.f;
    for (int e = start; e < end; ++e) {
        const int c = col[e];
        const float w = wgt[e];
        half8 v = *(const half8*)(ht + ((size_t)c * BWn + s) * Hn + g);  // contiguous 4 KB/edge
        #pragma unroll
        for (int j = 0; j < 8; ++j) acc[j] = fmaf(w, (float)v[j], acc[j]);
    }
    half8 o;
    #pragma unroll
    for (int j = 0; j < 8; ++j) o[j] = (_Float16)fmaxf(acc[j] + bias[g + j], 0.f);
    *(half8*)(out + ((size_t)n * BWn + s) * Hn + g) = o;                 // contiguous 4 KB/node
}

// ---------------- fully fused LSTM (h2 rows in (n,s) order) ----------------
// grid 625 x 512 threads (8 waves); block owns 32 batch rows. Wave nw owns h-cols
// nw*16..+15 for ALL 4 gates. Weights register-cached in B-frag layout. x double-
// buffered in LDS; h in LDS; c in registers. Pointwise via v_exp/v_rcp.
__global__ __launch_bounds__(512, 1) void lstm_fused2_kernel(
    const _Float16* __restrict__ h2, const _Float16* __restrict__ wif,
    const _Float16* __restrict__ whf, const float* __restrict__ bsum,
    _Float16* __restrict__ hf) {
    __shared__ __align__(16) _Float16 x_lds[2][LROWS][144];
    __shared__ __align__(16) _Float16 h_lds[LROWS][144];
    const int tid = threadIdx.x;
    const int nw = tid >> 6, lane = tid & 63;
    const int l = lane & 15, q = lane >> 4;
    const int r0 = blockIdx.x * LROWS;
    const int srow = tid >> 4, sch = (tid & 15) * 8;
    const int sgrow = r0 + srow;
    const int sb = (sgrow >= Nn) ? 1 : 0;
    const int sn = sgrow - sb * Nn;
    const _Float16* xbase = h2 + ((size_t)sn * BWn + sb * Wn) * 128 + sch;

    half8 wic[4][4], whc[4][4];
    #pragma unroll
    for (int g = 0; g < 4; ++g) {
        int ct = g * 8 + nw;
        #pragma unroll
        for (int kt = 0; kt < 4; ++kt) {
            wic[g][kt] = *(const half8*)(wif + (((size_t)ct * 4 + kt) * 64 + lane) * 8);
            whc[g][kt] = *(const half8*)(whf + (((size_t)ct * 4 + kt) * 64 + lane) * 8);
        }
    }
    float bias[4];
    #pragma unroll
    for (int g = 0; g < 4; ++g) bias[g] = bsum[g * 128 + nw * 16 + l];
    float c_reg[2][4];
    #pragma unroll
    for (int i = 0; i < 2; ++i)
        #pragma unroll
        for (int r = 0; r < 4; ++r) c_reg[i][r] = 0.f;

    *(half8*)&x_lds[0][srow][sch] = *(const half8*)(xbase);
    __syncthreads();

    for (int t = 0; t < Wn; ++t) {
        half8 xv = {0, 0, 0, 0, 0, 0, 0, 0};
        if (t + 1 < Wn) xv = *(const half8*)(xbase + (size_t)(t + 1) * 128);

        f32x4 acc[2][4];
        #pragma unroll
        for (int i = 0; i < 2; ++i)
            #pragma unroll
            for (int g = 0; g < 4; ++g)
                acc[i][g] = (f32x4){bias[g], bias[g], bias[g], bias[g]};

        #pragma unroll
        for (int kt = 0; kt < 4; ++kt) {
            half8 af[2];
            #pragma unroll
            for (int i = 0; i < 2; ++i)
                af[i] = *(const half8*)&x_lds[t & 1][i * 16 + l][kt * 32 + q * 8];
            #pragma unroll
            for (int i = 0; i < 2; ++i)
                #pragma unroll
                for (int g = 0; g < 4; ++g)
                    acc[i][g] = __builtin_amdgcn_mfma_f32_16x16x32_f16(
                        af[i], wic[g][kt], acc[i][g], 0, 0, 0);
        }
        if (t > 0) {
            #pragma unroll
            for (int kt = 0; kt < 4; ++kt) {
                half8 af[2];
                #pragma unroll
                for (int i = 0; i < 2; ++i)
                    af[i] = *(const half8*)&h_lds[i * 16 + l][kt * 32 + q * 8];
                #pragma unroll
                for (int i = 0; i < 2; ++i)
                    #pragma unroll
                    for (int g = 0; g < 4; ++g)
                        acc[i][g] = __builtin_amdgcn_mfma_f32_16x16x32_f16(
                            af[i], whc[g][kt], acc[i][g], 0, 0, 0);
            }
        }
        __syncthreads();

        #pragma unroll
        for (int i = 0; i < 2; ++i) {
            #pragma unroll
            for (int r = 0; r < 4; ++r) {
                float si = fast_sigmoid(acc[i][0][r]);
                float sf = fast_sigmoid(acc[i][1][r]);
                float tg = fast_tanh(acc[i][2][r]);
                float so = fast_sigmoid(acc[i][3][r]);
                float cn = sf * c_reg[i][r] + si * tg;
                c_reg[i][r] = cn;
                h_lds[i * 16 + q * 4 + r][nw * 16 + l] = (_Float16)(so * fast_tanh(cn));
            }
        }
        if (t + 1 < Wn) *(half8*)&x_lds[(t + 1) & 1][srow][sch] = xv;
        __syncthreads();
    }
    *(half8*)(hf + (size_t)sgrow * 128 + sch) = *(const half8*)&h_lds[srow][sch];
}

// ---------------- decoder ----------------
__global__ __launch_bounds__(256) void decoder_kernel(
    const _Float16* __restrict__ h, const float* __restrict__ w1,
    const float* __restrict__ b1, const float* __restrict__ w2,
    const float* __restrict__ b2, float* __restrict__ out) {
    const int wave = threadIdx.x >> 6;
    const int lane = threadIdx.x & 63;
    const int row = blockIdx.x * 4 + wave;
    if (row >= MR) return;
    const _Float16* hr = h + (size_t)row * Hn;
    float d = b1[lane];
    #pragma unroll 8
    for (int k = 0; k < Hn; ++k) d = fmaf((float)hr[k], w1[k * 64 + lane], d);
    d = fmaxf(d, 0.f);
    float p = d * w2[lane];
    #pragma unroll
    for (int off = 32; off; off >>= 1) p += __shfl_down(p, off);
    if (lane == 0) out[row] = p + b2[0];
}

// ---------------- launch ----------------

extern "C" void kernel_launch(void* const* d_in, const int* in_sizes, int n_in,
                              void* d_out, int out_size, void* d_ws, size_t ws_size,
                              hipStream_t stream) {
    const float* x   = (const float*)d_in[0];
    const int*   ei  = (const int*)d_in[1];
    const float* g1w = (const float*)d_in[2];
    const float* g1b = (const float*)d_in[3];
    const float* g2w = (const float*)d_in[4];
    const float* g2b = (const float*)d_in[5];
    const float* wih = (const float*)d_in[6];
    const float* whh = (const float*)d_in[7];
    const float* bih = (const float*)d_in[8];
    const float* bhh = (const float*)d_in[9];
    const float* dw1 = (const float*)d_in[10];
    const float* db1 = (const float*)d_in[11];
    const float* dw2 = (const float*)d_in[12];
    const float* db2 = (const float*)d_in[13];
    float* out = (float*)d_out;

    char* p = (char*)d_ws;
    auto alloc = [&](size_t bytes) {
        char* r = p;
        p += (bytes + 255) & ~(size_t)255;
        return r;
    };
    int*      counts   = (int*)     alloc(Nn * 4);
    int*      row_ptr  = (int*)     alloc((Nn + 1) * 4);
    int*      fill_ptr = (int*)     alloc((Nn + 1) * 4);
    float*    dinv     = (float*)   alloc(Nn * 4);
    float*    bsum     = (float*)   alloc(4 * Hn * 4);
    int*      col      = (int*)     alloc((En + Nn) * 4);
    float*    wgt      = (float*)   alloc((En + Nn) * 4);
    _Float16* wif      = (_Float16*)alloc(512 * 128 * 2);
    _Float16* whf      = (_Float16*)alloc(512 * 128 * 2);
    _Float16* g2wt     = (_Float16*)alloc(128 * 128 * 2);
    float*    aggx     = (float*)   alloc((size_t)ROWS * Fin * 4);    // 3.2 MB
    _Float16* htf      = (_Float16*)alloc((size_t)ROWS * Hn * 2);     // 41 MB
    _Float16* h2f      = (_Float16*)alloc((size_t)ROWS * Hn * 2);     // 41 MB
    _Float16* hf       = (_Float16*)alloc((size_t)MR * Hn * 2);       // 5.1 MB

    // ---- CSR build + weight prep ----
    init_counts_kernel<<<(Nn + 255) / 256, 256, 0, stream>>>(counts);
    count_edges_kernel<<<(En + 255) / 256, 256, 0, stream>>>(ei, counts);
    scan_kernel<<<1, 1024, 0, stream>>>(counts, row_ptr, fill_ptr, dinv);
    fill_kernel<<<(Nn + En + 255) / 256, 256, 0, stream>>>(ei, dinv, fill_ptr, col, wgt);
    bsum_kernel<<<(4 * Hn + 255) / 256, 256, 0, stream>>>(bih, bhh, bsum);
    convert_w_kernel<<<(131072 + 16384 + 255) / 256, 256, 0, stream>>>(
        wih, whh, g2w, wif, whf, g2wt);

    // ---- GCN layer 1 aggregation (writes (n,s) order) ----
    agg_x_kernel<<<Nn, 128, 0, stream>>>(x, row_ptr, col, wgt, aggx);

    // ---- fused GCN1-transform + GCN2-transform (MFMA) ----
    gcn2_fused_kernel<<<ROWS / 128, 256, 0, stream>>>(aggx, g1w, g1b, g2wt, htf);

    // ---- GCN layer 2 aggregation (contiguous gathers) ----
    gcn_agg2_kernel<<<Nn, 256, 0, stream>>>(htf, row_ptr, col, wgt, g2b, h2f);

    // ---- fully fused LSTM ----
    lstm_fused2_kernel<<<MR / LROWS, 512, 0, stream>>>(h2f, wif, whf, bsum, hf);

    // ---- decoder ----
    decoder_kernel<<<(MR + 3) / 4, 256, 0, stream>>>(hf, dw1, db1, dw2, db2, out);
}